// Round 1
// baseline (481.272 us; speedup 1.0000x reference)
//
#include <hip/hip_runtime.h>
#include <math.h>

#define VOCAB 32000
#define NB 16        // batch
#define NH 12        // heads
#define DEC_T 128
#define ALEN 512
#define DD 768
#define NT 1024      // threads per block
#define NW 16        // waves per block
#define V4 8000      // VOCAB/4 float4 per row
#define CHUNKS 8     // ceil(V4/NT)

__device__ inline float wave_sum(float v) {
#pragma unroll
  for (int o = 32; o > 0; o >>= 1) v += __shfl_down(v, o, 64);
  return v;
}
__device__ inline float wave_max(float v) {
#pragma unroll
  for (int o = 32; o > 0; o >>= 1) v = fmaxf(v, __shfl_down(v, o, 64));
  return v;
}

__global__ __launch_bounds__(NT, 4) void pg_kernel(
    const float* __restrict__ dec, const float* __restrict__ fo,
    const float* __restrict__ attnw, const int* __restrict__ ids,
    const float* __restrict__ Wpg, const float* __restrict__ bpg,
    float* __restrict__ out) {
  __shared__ float s_vocab[VOCAB];   // 128000 B scatter buffer
  __shared__ float s_red[NW];
  __shared__ float s_res[8];

  const int bt = blockIdx.x;          // b*DEC_T + t
  const int b = bt / DEC_T;
  const int t = bt - b * DEC_T;
  const int tid = threadIdx.x;
  const int lane = tid & 63;
  const int wid = tid >> 6;

  // ---- issue the row loads early; they stay in flight during pgen/attn ----
  const float4* row4 = (const float4*)(fo + (size_t)bt * VOCAB);
  float4 r[CHUNKS];
#pragma unroll
  for (int c = 0; c < CHUNKS; ++c) {
    int idx = c * NT + tid;
    if (idx < V4) r[c] = row4[idx];
  }

  // ---- zero scatter buffer ----
  for (int i = tid; i < VOCAB; i += NT) s_vocab[i] = 0.f;

  // ---- p_gen = sigmoid(dec[bt,:] . Wpg + b) ----
  float pp = 0.f;
  if (tid < DD) pp = dec[(size_t)bt * DD + tid] * Wpg[tid];
  pp = wave_sum(pp);
  if (lane == 0) s_red[wid] = pp;
  __syncthreads();
  if (tid == 0) {
    float acc = 0.f;
    for (int i = 0; i < NW; ++i) acc += s_red[i];
    s_res[0] = acc;
  }
  __syncthreads();
  const float pgen = 1.f / (1.f + __expf(-(s_res[0] + bpg[0])));

  // ---- attention: mean over heads, softmax over ALEN ----
  float amean = 0.f;
  float av = -INFINITY;
  if (tid < ALEN) {
    const float* ap = attnw + ((size_t)b * NH * DEC_T + t) * ALEN + tid;
    float s = 0.f;
#pragma unroll
    for (int h = 0; h < NH; ++h) s += ap[(size_t)h * DEC_T * ALEN];
    amean = s * (1.f / NH);
    av = amean;
  }
  float am = wave_max(av);
  if (lane == 0) s_red[wid] = am;
  __syncthreads();
  if (tid == 0) {
    float acc = -INFINITY;
    for (int i = 0; i < NW; ++i) acc = fmaxf(acc, s_red[i]);
    s_res[1] = acc;
  }
  __syncthreads();
  const float amax = s_res[1];
  float ae = (tid < ALEN) ? __expf(amean - amax) : 0.f;
  float as = wave_sum(ae);
  if (lane == 0) s_red[wid] = as;
  __syncthreads();
  if (tid == 0) {
    float acc = 0.f;
    for (int i = 0; i < NW; ++i) acc += s_red[i];
    s_res[2] = acc;
  }
  __syncthreads();
  const float ainv = (1.f - pgen) / s_res[2];
  // scatter: duplicates combined via LDS atomics (s_vocab zeroing is
  // complete — several __syncthreads passed since the zero loop)
  if (tid < ALEN) atomicAdd(&s_vocab[ids[b * ALEN + tid]], ae * ainv);

  // ---- vocab softmax: max ----
  float m = -INFINITY;
#pragma unroll
  for (int c = 0; c < CHUNKS; ++c) {
    int idx = c * NT + tid;
    if (idx < V4)
      m = fmaxf(m, fmaxf(fmaxf(r[c].x, r[c].y), fmaxf(r[c].z, r[c].w)));
  }
  m = wave_max(m);
  if (lane == 0) s_red[wid] = m;
  __syncthreads();
  if (tid == 0) {
    float acc = -INFINITY;
    for (int i = 0; i < NW; ++i) acc = fmaxf(acc, s_red[i]);
    s_res[3] = acc;
  }
  __syncthreads();
  const float fm = s_res[3];

  // ---- vocab softmax: denominator ----
  float zs = 0.f;
#pragma unroll
  for (int c = 0; c < CHUNKS; ++c) {
    int idx = c * NT + tid;
    if (idx < V4)
      zs += __expf(r[c].x - fm) + __expf(r[c].y - fm) +
            __expf(r[c].z - fm) + __expf(r[c].w - fm);
  }
  zs = wave_sum(zs);
  if (lane == 0) s_red[wid] = zs;
  __syncthreads();
  if (tid == 0) {
    float acc = 0.f;
    for (int i = 0; i < NW; ++i) acc += s_red[i];
    s_res[4] = acc;
  }
  __syncthreads();  // also guarantees scatter atomics are visible
  const float Z = s_res[4];
  const float invZ = 1.f / Z;
  const float C = __logf(pgen) - fm - __logf(Z);

  // ---- output: log(pgen*softmax + scatter) ----
  // scatter==0 (the common case): log(pgen*exp(x-m)/Z) = x + C  (no exp/log)
  float4* out4 = (float4*)(out + (size_t)bt * VOCAB);
#pragma unroll
  for (int c = 0; c < CHUNKS; ++c) {
    int idx = c * NT + tid;
    if (idx < V4) {
      const int v = idx * 4;
      const float4 x = r[c];
      const float s0 = s_vocab[v + 0];
      const float s1 = s_vocab[v + 1];
      const float s2 = s_vocab[v + 2];
      const float s3 = s_vocab[v + 3];
      float4 o;
      o.x = (s0 == 0.f) ? (x.x + C) : __logf(pgen * __expf(x.x - fm) * invZ + s0);
      o.y = (s1 == 0.f) ? (x.y + C) : __logf(pgen * __expf(x.y - fm) * invZ + s1);
      o.z = (s2 == 0.f) ? (x.z + C) : __logf(pgen * __expf(x.z - fm) * invZ + s2);
      o.w = (s3 == 0.f) ? (x.w + C) : __logf(pgen * __expf(x.w - fm) * invZ + s3);
      out4[idx] = o;
    }
  }
}

extern "C" void kernel_launch(void* const* d_in, const int* in_sizes, int n_in,
                              void* d_out, int out_size, void* d_ws, size_t ws_size,
                              hipStream_t stream) {
  (void)in_sizes; (void)n_in; (void)out_size; (void)d_ws; (void)ws_size;
  const float* dec   = (const float*)d_in[0];   // (16,128,768)
  const float* fo    = (const float*)d_in[1];   // (16,128,32000)
  const float* attnw = (const float*)d_in[2];   // (16,12,128,512)
  const int*   ids   = (const int*)  d_in[3];   // (16,512)
  const float* Wpg   = (const float*)d_in[4];   // (768,1)
  const float* bpg   = (const float*)d_in[5];   // (1,)
  float* out = (float*)d_out;                   // (16,128,32000)

  pg_kernel<<<NB * DEC_T, NT, 0, stream>>>(dec, fo, attnw, ids, Wpg, bpg, out);
}